// Round 2
// baseline (462.159 us; speedup 1.0000x reference)
//
#include <hip/hip_runtime.h>

#define T_STEPS 20
#define BATCH   65536
#define HIDN    64
#define GATES   256
#define ROWS_PER_WAVE 32
#define ROWS_PER_WG   128   // 4 waves * 32 rows

typedef __bf16 bf16x8 __attribute__((ext_vector_type(8)));
typedef float  f32x4  __attribute__((ext_vector_type(4)));

#if __has_builtin(__builtin_amdgcn_exp2f)
#define EXP2F(x) __builtin_amdgcn_exp2f(x)
#else
#define EXP2F(x) exp2f(x)
#endif
#if __has_builtin(__builtin_amdgcn_rcpf)
#define RCPF(x) __builtin_amdgcn_rcpf(x)
#else
#define RCPF(x) (1.0f / (x))
#endif

__device__ __forceinline__ float sigmoid_f(float x) {
    return RCPF(1.0f + EXP2F(x * -1.4426950408889634f));
}
__device__ __forceinline__ float tanh_f(float x) {
    return 1.0f - 2.0f * RCPF(1.0f + EXP2F(x * 2.8853900817779268f));
}

__global__ __launch_bounds__(256, 2)
void Encoder_6949257085628_kernel(const float* __restrict__ obs,
                                  const float* __restrict__ W_emb,
                                  const float* __restrict__ b_emb,
                                  const float* __restrict__ W_ih,
                                  const float* __restrict__ W_hh,
                                  const float* __restrict__ b_ih,
                                  const float* __restrict__ b_hh,
                                  float* __restrict__ out) {
    __shared__ __align__(16) __bf16 whh_l[16384];          // 32 KB, B-fragment order
    __shared__ __align__(16) __bf16 hl[4 * ROWS_PER_WAVE * 72]; // 18 KB per-wave h tiles
    __shared__ __align__(16) float  wcbc[GATES * 3];       // 3 KB

    const int tid = threadIdx.x;
    const int wg  = blockIdx.x;
    const int rowBase = wg * ROWS_PER_WG;

    // ---- stage W_hh -> bf16 in MFMA B-fragment layout ----
    // B[k][n] = W_hh[n][k]; frag (ct,ks): lane l holds n=ct*16+(l&15), k=ks*32+(l>>4)*8+j
    for (int idx = tid; idx < 16384; idx += 256) {
        int n = idx >> 6, k = idx & 63;
        float v = W_hh[idx];
        int ct = n >> 4;
        int ln = (n & 15) | (((k >> 3) & 3) << 4);
        int ks = k >> 5;
        int j  = k & 7;
        whh_l[((ct * 2 + ks) * 64 + ln) * 8 + j] = (__bf16)v;
    }
    // ---- fold embedding into gate map: Wc (256x2), bc (256) ----
    {
        int g = tid;  // exactly 256 threads
        float a0 = 0.f, a1 = 0.f, ab = 0.f;
        for (int e = 0; e < 64; ++e) {
            float wie = W_ih[g * 64 + e];
            a0 = fmaf(wie, W_emb[e * 2 + 0], a0);
            a1 = fmaf(wie, W_emb[e * 2 + 1], a1);
            ab = fmaf(wie, b_emb[e], ab);
        }
        wcbc[g * 3 + 0] = a0;
        wcbc[g * 3 + 1] = a1;
        wcbc[g * 3 + 2] = ab + b_ih[g] + b_hh[g];
    }
    __syncthreads();

    const int lane = tid & 63;
    const int wave = tid >> 6;
    const int q    = lane >> 4;   // 0..3
    const int c16  = lane & 15;
    __bf16* hlw = &hl[wave * (ROWS_PER_WAVE * 72)];
    const int rbw = rowBase + wave * ROWS_PER_WAVE;

    // per-lane gate-column constants (col = ti*16 + c16)
    float w0[16], w1[16], bc[16];
    #pragma unroll
    for (int ti = 0; ti < 16; ++ti) {
        int g = ti * 16 + c16;
        w0[ti] = wcbc[g * 3 + 0];
        w1[ti] = wcbc[g * 3 + 1];
        bc[ti] = wcbc[g * 3 + 2];
    }

    f32x4 acc[2][16];
    float cst[2][16];
    #pragma unroll
    for (int mt = 0; mt < 2; ++mt)
        #pragma unroll
        for (int i = 0; i < 16; ++i) cst[mt][i] = 0.f;

    // prefetch x for t=0: rows rbw + mt*16 + q*4 + r
    float2 xc[2][4];
    #pragma unroll
    for (int mt = 0; mt < 2; ++mt)
        #pragma unroll
        for (int r = 0; r < 4; ++r)
            xc[mt][r] = *(const float2*)&obs[(size_t)(rbw + mt * 16 + q * 4 + r) * 2];

    #pragma unroll 1
    for (int t = 0; t < T_STEPS; ++t) {
        // prefetch next step's x
        float2 xn[2][4];
        {
            int tn = (t < T_STEPS - 1) ? t + 1 : t;
            const float* ob = obs + (size_t)tn * (BATCH * 2);
            #pragma unroll
            for (int mt = 0; mt < 2; ++mt)
                #pragma unroll
                for (int r = 0; r < 4; ++r)
                    xn[mt][r] = *(const float2*)&ob[(size_t)(rbw + mt * 16 + q * 4 + r) * 2];
        }
        // ---- init accumulators with x-contribution + bias ----
        #pragma unroll
        for (int mt = 0; mt < 2; ++mt)
            #pragma unroll
            for (int ti = 0; ti < 16; ++ti)
                #pragma unroll
                for (int r = 0; r < 4; ++r)
                    acc[mt][ti][r] = fmaf(xc[mt][r].y, w1[ti],
                                     fmaf(xc[mt][r].x, w0[ti], bc[ti]));

        // ---- recurrent GEMM: gates += h @ W_hh^T (bf16 MFMA) ----
        if (t > 0) {
            bf16x8 a0[2], a1[2];
            #pragma unroll
            for (int mt = 0; mt < 2; ++mt) {
                a0[mt] = *(bf16x8*)&hlw[(mt * 16 + c16) * 72 + q * 8];
                a1[mt] = *(bf16x8*)&hlw[(mt * 16 + c16) * 72 + 32 + q * 8];
            }
            #pragma unroll
            for (int ti = 0; ti < 16; ++ti) {
                bf16x8 b0 = *(bf16x8*)&whh_l[((ti * 2 + 0) * 64 + lane) * 8];
                acc[0][ti] = __builtin_amdgcn_mfma_f32_16x16x32_bf16(a0[0], b0, acc[0][ti], 0, 0, 0);
                acc[1][ti] = __builtin_amdgcn_mfma_f32_16x16x32_bf16(a0[1], b0, acc[1][ti], 0, 0, 0);
                bf16x8 b1 = *(bf16x8*)&whh_l[((ti * 2 + 1) * 64 + lane) * 8];
                acc[0][ti] = __builtin_amdgcn_mfma_f32_16x16x32_bf16(a1[0], b1, acc[0][ti], 0, 0, 0);
                acc[1][ti] = __builtin_amdgcn_mfma_f32_16x16x32_bf16(a1[1], b1, acc[1][ti], 0, 0, 0);
            }
        }

        // ---- activations + state update ----
        // lane holds gates[row=q*4+r][col=ti*16+c16]; hidden j = jt*16+c16
        #pragma unroll
        for (int mt = 0; mt < 2; ++mt) {
            #pragma unroll
            for (int jt = 0; jt < 4; ++jt) {
                #pragma unroll
                for (int r = 0; r < 4; ++r) {
                    float ig = sigmoid_f(acc[mt][jt][r]);
                    float fg = sigmoid_f(acc[mt][4 + jt][r]);
                    float gg = tanh_f(acc[mt][8 + jt][r]);
                    float og = sigmoid_f(acc[mt][12 + jt][r]);
                    float c  = fmaf(fg, cst[mt][jt * 4 + r], ig * gg);
                    cst[mt][jt * 4 + r] = c;
                    float h = og * tanh_f(c);
                    if (t < T_STEPS - 1) {
                        hlw[(mt * 16 + q * 4 + r) * 72 + jt * 16 + c16] = (__bf16)h;
                    } else {
                        out[(size_t)(rbw + mt * 16 + q * 4 + r) * HIDN + jt * 16 + c16] = h;
                    }
                }
            }
        }

        #pragma unroll
        for (int mt = 0; mt < 2; ++mt)
            #pragma unroll
            for (int r = 0; r < 4; ++r)
                xc[mt][r] = xn[mt][r];
    }
}

extern "C" void kernel_launch(void* const* d_in, const int* in_sizes, int n_in,
                              void* d_out, int out_size, void* d_ws, size_t ws_size,
                              hipStream_t stream) {
    const float* obs   = (const float*)d_in[0];
    const float* W_emb = (const float*)d_in[1];
    const float* b_emb = (const float*)d_in[2];
    const float* W_ih  = (const float*)d_in[3];
    const float* W_hh  = (const float*)d_in[4];
    const float* b_ih  = (const float*)d_in[5];
    const float* b_hh  = (const float*)d_in[6];
    float* out = (float*)d_out;

    dim3 grid(BATCH / ROWS_PER_WG);  // 512
    dim3 block(256);
    Encoder_6949257085628_kernel<<<grid, block, 0, stream>>>(
        obs, W_emb, b_emb, W_ih, W_hh, b_ih, b_hh, out);
}

// Round 3
// 265.566 us; speedup vs baseline: 1.7403x; 1.7403x over previous
//
#include <hip/hip_runtime.h>

#define T_STEPS 20
#define BATCH   65536
#define HIDN    64
#define GATES   256
#define ROWS_PER_WG 64   // 4 waves * 16 rows

typedef __bf16 bf16x8 __attribute__((ext_vector_type(8)));
typedef float  f32x4  __attribute__((ext_vector_type(4)));

#if __has_builtin(__builtin_amdgcn_exp2f)
#define EXP2F(x) __builtin_amdgcn_exp2f(x)
#else
#define EXP2F(x) exp2f(x)
#endif
#if __has_builtin(__builtin_amdgcn_rcpf)
#define RCPF(x) __builtin_amdgcn_rcpf(x)
#else
#define RCPF(x) (1.0f / (x))
#endif

__device__ __forceinline__ float sigmoid_f(float x) {
    return RCPF(1.0f + EXP2F(x * -1.4426950408889634f));
}
__device__ __forceinline__ float tanh_f(float x) {
    return 1.0f - 2.0f * RCPF(1.0f + EXP2F(x * 2.8853900817779268f));
}

__global__ __launch_bounds__(256, 2)
void Encoder_6949257085628_kernel(const float* __restrict__ obs,
                                  const float* __restrict__ W_emb,
                                  const float* __restrict__ b_emb,
                                  const float* __restrict__ W_ih,
                                  const float* __restrict__ W_hh,
                                  const float* __restrict__ b_ih,
                                  const float* __restrict__ b_hh,
                                  float* __restrict__ out) {
    __shared__ __align__(16) __bf16 whh_l[16384];       // 32 KB, B-fragment order
    __shared__ __align__(16) float  wcbc[GATES * 3];    // 3 KB
    __shared__ __align__(16) __bf16 hl[4 * 16 * 72];    // 9 KB per-wave h tiles

    const int tid = threadIdx.x;
    const int wg  = blockIdx.x;
    const int rowBase = wg * ROWS_PER_WG;

    // ---- stage W_hh -> bf16 in MFMA B-fragment layout ----
    // B[k][n] = W_hh[n][k]; frag (ct,ks): lane l holds n=ct*16+(l&15), k=ks*32+(l>>4)*8+j
    for (int idx = tid; idx < 16384; idx += 256) {
        int n = idx >> 6, k = idx & 63;
        float v = W_hh[idx];
        int ct = n >> 4;
        int ln = (n & 15) | (((k >> 3) & 3) << 4);
        int ks = k >> 5;
        int j  = k & 7;
        whh_l[((ct * 2 + ks) * 64 + ln) * 8 + j] = (__bf16)v;
    }
    // ---- fold embedding into gate map: Wc (256x2), bc (256) ----
    {
        int g = tid;  // exactly 256 threads
        float a0 = 0.f, a1 = 0.f, ab = 0.f;
        for (int e = 0; e < 64; ++e) {
            float wie = W_ih[g * 64 + e];
            a0 = fmaf(wie, W_emb[e * 2 + 0], a0);
            a1 = fmaf(wie, W_emb[e * 2 + 1], a1);
            ab = fmaf(wie, b_emb[e], ab);
        }
        wcbc[g * 3 + 0] = a0;
        wcbc[g * 3 + 1] = a1;
        wcbc[g * 3 + 2] = ab + b_ih[g] + b_hh[g];
    }
    __syncthreads();   // the ONLY barrier: whh_l/wcbc staged

    const int lane = tid & 63;
    const int wave = tid >> 6;
    const int q    = lane >> 4;   // 0..3
    const int c16  = lane & 15;
    __bf16* hlw = &hl[wave * (16 * 72)];
    const int rbw = rowBase + wave * 16;

    // per-lane gate-column constants (col = ti*16 + c16)
    float w0[16], w1[16], bc[16];
    #pragma unroll
    for (int ti = 0; ti < 16; ++ti) {
        int g = ti * 16 + c16;
        w0[ti] = wcbc[g * 3 + 0];
        w1[ti] = wcbc[g * 3 + 1];
        bc[ti] = wcbc[g * 3 + 2];
    }

    f32x4 acc[16];
    float cst[16];
    #pragma unroll
    for (int i = 0; i < 16; ++i) cst[i] = 0.f;

    // prefetch x for t=0: rows rbw + q*4 + r
    float2 xc[4];
    #pragma unroll
    for (int r = 0; r < 4; ++r)
        xc[r] = *(const float2*)&obs[(size_t)(rbw + q * 4 + r) * 2];

    #pragma unroll 1
    for (int t = 0; t < T_STEPS; ++t) {
        // prefetch next step's x
        float2 xn[4];
        {
            int tn = (t < T_STEPS - 1) ? t + 1 : t;
            const float* ob = obs + (size_t)tn * (BATCH * 2);
            #pragma unroll
            for (int r = 0; r < 4; ++r)
                xn[r] = *(const float2*)&ob[(size_t)(rbw + q * 4 + r) * 2];
        }
        // ---- init accumulators with x-contribution + bias ----
        #pragma unroll
        for (int ti = 0; ti < 16; ++ti)
            #pragma unroll
            for (int r = 0; r < 4; ++r)
                acc[ti][r] = fmaf(xc[r].y, w1[ti], fmaf(xc[r].x, w0[ti], bc[ti]));

        // ---- recurrent GEMM: gates += h @ W_hh^T (bf16 MFMA); h==0 at t=0 ----
        if (t > 0) {
            bf16x8 a0 = *(bf16x8*)&hlw[c16 * 72 + q * 8];
            bf16x8 a1 = *(bf16x8*)&hlw[c16 * 72 + 32 + q * 8];
            #pragma unroll
            for (int ti = 0; ti < 16; ++ti) {
                bf16x8 b0 = *(bf16x8*)&whh_l[((ti * 2 + 0) * 64 + lane) * 8];
                acc[ti] = __builtin_amdgcn_mfma_f32_16x16x32_bf16(a0, b0, acc[ti], 0, 0, 0);
                bf16x8 b1 = *(bf16x8*)&whh_l[((ti * 2 + 1) * 64 + lane) * 8];
                acc[ti] = __builtin_amdgcn_mfma_f32_16x16x32_bf16(a1, b1, acc[ti], 0, 0, 0);
            }
        }

        // ---- activations + state update ----
        // lane holds gates[row=q*4+r][col=ti*16+c16]; hidden j = jt*16+c16
        #pragma unroll
        for (int jt = 0; jt < 4; ++jt) {
            #pragma unroll
            for (int r = 0; r < 4; ++r) {
                float ig = sigmoid_f(acc[jt][r]);
                float fg = sigmoid_f(acc[4 + jt][r]);
                float gg = tanh_f(acc[8 + jt][r]);
                float og = sigmoid_f(acc[12 + jt][r]);
                float c  = fmaf(fg, cst[jt * 4 + r], ig * gg);
                cst[jt * 4 + r] = c;
                float h = og * tanh_f(c);
                if (t < T_STEPS - 1) {
                    hlw[(q * 4 + r) * 72 + jt * 16 + c16] = (__bf16)h;
                } else {
                    out[(size_t)(rbw + q * 4 + r) * HIDN + jt * 16 + c16] = h;
                }
            }
        }

        #pragma unroll
        for (int r = 0; r < 4; ++r) xc[r] = xn[r];
        // NO __syncthreads(): hl tiles are wave-private; intra-wave LDS
        // ordering is enforced by compiler lgkmcnt waits.
    }
}

extern "C" void kernel_launch(void* const* d_in, const int* in_sizes, int n_in,
                              void* d_out, int out_size, void* d_ws, size_t ws_size,
                              hipStream_t stream) {
    const float* obs   = (const float*)d_in[0];
    const float* W_emb = (const float*)d_in[1];
    const float* b_emb = (const float*)d_in[2];
    const float* W_ih  = (const float*)d_in[3];
    const float* W_hh  = (const float*)d_in[4];
    const float* b_ih  = (const float*)d_in[5];
    const float* b_hh  = (const float*)d_in[6];
    float* out = (float*)d_out;

    dim3 grid(BATCH / ROWS_PER_WG);  // 1024
    dim3 block(256);
    Encoder_6949257085628_kernel<<<grid, block, 0, stream>>>(
        obs, W_emb, b_emb, W_ih, W_hh, b_ih, b_hh, out);
}

// Round 4
// 143.157 us; speedup vs baseline: 3.2283x; 1.8551x over previous
//
#include <hip/hip_runtime.h>

#define T_STEPS 20
#define BATCH   65536
#define HIDN    64
#define GATES   256
#define CHUNKS  4        // 16-row chunks per persistent WG
#define HSTR    72       // hl row stride (bf16 elems)

typedef __bf16 bf16x8 __attribute__((ext_vector_type(8)));
typedef float  f32x4  __attribute__((ext_vector_type(4)));
typedef float  f32x2  __attribute__((ext_vector_type(2)));

#if __has_builtin(__builtin_amdgcn_exp2f)
#define EXP2F(x) __builtin_amdgcn_exp2f(x)
#else
#define EXP2F(x) exp2f(x)
#endif
#if __has_builtin(__builtin_amdgcn_rcpf)
#define RCPF(x) __builtin_amdgcn_rcpf(x)
#else
#define RCPF(x) (1.0f / (x))
#endif

__device__ __forceinline__ float sigmoid_f(float x) {
    return RCPF(1.0f + EXP2F(x * -1.4426950408889634f));
}
__device__ __forceinline__ float tanh_f(float x) {
    return 1.0f - 2.0f * RCPF(1.0f + EXP2F(x * 2.8853900817779268f));
}

// WG = 4 waves = 16 batch rows. Wave jtw owns hidden slice [16*jtw, 16*jtw+16):
// it computes gate tiles {jtw, 4+jtw, 8+jtw, 12+jtw} (i,f,g,o for its slice),
// holding the 8 needed W_hh B-fragments in REGISTERS (32 VGPR) for the whole
// kernel. Steady-state LDS = 2x ds_read_b128 (h A-frags) + 4x ds_write_b16
// (h quarter) per wave/step, double-buffered, one barrier per step.
__global__ __launch_bounds__(256, 4)
void Encoder_6949257085628_kernel(const float* __restrict__ obs,
                                  const float* __restrict__ W_emb,
                                  const float* __restrict__ b_emb,
                                  const float* __restrict__ W_ih,
                                  const float* __restrict__ W_hh,
                                  const float* __restrict__ b_ih,
                                  const float* __restrict__ b_hh,
                                  float* __restrict__ out) {
    __shared__ float wcbc[GATES * 3];                    // 3 KB
    __shared__ __align__(16) __bf16 hlb[2][16 * HSTR];   // 2 x 2.25 KB, dbuf

    const int tid  = threadIdx.x;
    const int jtw  = tid >> 6;       // wave index = hidden-quarter
    const int lane = tid & 63;
    const int q    = lane >> 4;      // 0..3
    const int c16  = lane & 15;

    // ---- fold embedding into gate map: Wc (256x2), bc (256) ----
    {
        int g = tid;  // exactly 256 threads
        float a0 = 0.f, a1 = 0.f, ab = 0.f;
        for (int e = 0; e < 64; ++e) {
            float wie = W_ih[g * 64 + e];
            a0 = fmaf(wie, W_emb[e * 2 + 0], a0);
            a1 = fmaf(wie, W_emb[e * 2 + 1], a1);
            ab = fmaf(wie, b_emb[e], ab);
        }
        wcbc[g * 3 + 0] = a0;
        wcbc[g * 3 + 1] = a1;
        wcbc[g * 3 + 2] = ab + b_ih[g] + b_hh[g];
    }

    // ---- load this wave's 8 W_hh B-fragments into registers ----
    // B[k][n] = W_hh[n][k]; frag (tile,ks): lane holds n = tile*16+c16,
    // k = ks*32 + q*8 + j  (8 consecutive fp32 of one W_hh row).
    bf16x8 bfr[4][2];
    #pragma unroll
    for (int f = 0; f < 4; ++f) {
        const int rowW = (f * 4 + jtw) * 16 + c16;   // gate column
        #pragma unroll
        for (int ks = 0; ks < 2; ++ks) {
            const float* p = W_hh + rowW * 64 + ks * 32 + q * 8;
            f32x4 lo = *(const f32x4*)p;
            f32x4 hi = *(const f32x4*)(p + 4);
            bf16x8 b;
            b[0] = (__bf16)lo[0]; b[1] = (__bf16)lo[1];
            b[2] = (__bf16)lo[2]; b[3] = (__bf16)lo[3];
            b[4] = (__bf16)hi[0]; b[5] = (__bf16)hi[1];
            b[6] = (__bf16)hi[2]; b[7] = (__bf16)hi[3];
            bfr[f][ks] = b;
        }
    }
    __syncthreads();   // wcbc staged

    // per-lane x->gate constants for this wave's 4 gate columns
    float w0v[4], w1v[4], bcv[4];
    #pragma unroll
    for (int f = 0; f < 4; ++f) {
        int col = (f * 4 + jtw) * 16 + c16;   // = f*64 + jtw*16 + c16
        w0v[f] = wcbc[col * 3 + 0];
        w1v[f] = wcbc[col * 3 + 1];
        bcv[f] = wcbc[col * 3 + 2];
    }

    const int wgBase = blockIdx.x * (16 * CHUNKS);
    const int hOff   = jtw * 16 + c16;          // this lane's hidden index

    #pragma unroll 1
    for (int c = 0; c < CHUNKS; ++c) {
        const int rbw = wgBase + c * 16;

        float cst[4];
        #pragma unroll
        for (int r = 0; r < 4; ++r) cst[r] = 0.f;

        f32x2 xc[4];
        #pragma unroll
        for (int r = 0; r < 4; ++r)
            xc[r] = *(const f32x2*)&obs[(size_t)(rbw + q * 4 + r) * 2];

        #pragma unroll 1
        for (int t = 0; t < T_STEPS; ++t) {
            // prefetch next step's x
            f32x2 xn[4];
            {
                int tn = (t + 1 < T_STEPS) ? t + 1 : t;
                const float* ob = obs + (size_t)tn * (BATCH * 2);
                #pragma unroll
                for (int r = 0; r < 4; ++r)
                    xn[r] = *(const f32x2*)&ob[(size_t)(rbw + q * 4 + r) * 2];
            }

            // gate init: x-contribution + bias (fp32)
            f32x4 acc[4];
            #pragma unroll
            for (int f = 0; f < 4; ++f)
                #pragma unroll
                for (int r = 0; r < 4; ++r)
                    acc[f][r] = fmaf(xc[r][1], w1v[f],
                               fmaf(xc[r][0], w0v[f], bcv[f]));

            // recurrent GEMM for this wave's 4 gate tiles (h==0 at t=0)
            if (t > 0) {
                const __bf16* hp = hlb[(t & 1) ^ 1];
                bf16x8 a0 = *(const bf16x8*)&hp[c16 * HSTR + q * 8];
                bf16x8 a1 = *(const bf16x8*)&hp[c16 * HSTR + 32 + q * 8];
                #pragma unroll
                for (int f = 0; f < 4; ++f) {
                    acc[f] = __builtin_amdgcn_mfma_f32_16x16x32_bf16(a0, bfr[f][0], acc[f], 0, 0, 0);
                    acc[f] = __builtin_amdgcn_mfma_f32_16x16x32_bf16(a1, bfr[f][1], acc[f], 0, 0, 0);
                }
            }

            // activations + state update for (rows q*4+r, hidden hOff)
            __bf16* hw = hlb[t & 1];
            #pragma unroll
            for (int r = 0; r < 4; ++r) {
                float ig = sigmoid_f(acc[0][r]);
                float fg = sigmoid_f(acc[1][r]);
                float gg = tanh_f(acc[2][r]);
                float og = sigmoid_f(acc[3][r]);
                float cc = fmaf(fg, cst[r], ig * gg);
                cst[r] = cc;
                float h = og * tanh_f(cc);
                if (t < T_STEPS - 1) {
                    hw[(q * 4 + r) * HSTR + hOff] = (__bf16)h;
                } else {
                    out[(size_t)(rbw + q * 4 + r) * HIDN + hOff] = h;
                }
            }

            __syncthreads();  // h quarters exchanged; also guards chunk reuse

            #pragma unroll
            for (int r = 0; r < 4; ++r) xc[r] = xn[r];
        }
    }
}

extern "C" void kernel_launch(void* const* d_in, const int* in_sizes, int n_in,
                              void* d_out, int out_size, void* d_ws, size_t ws_size,
                              hipStream_t stream) {
    const float* obs   = (const float*)d_in[0];
    const float* W_emb = (const float*)d_in[1];
    const float* b_emb = (const float*)d_in[2];
    const float* W_ih  = (const float*)d_in[3];
    const float* W_hh  = (const float*)d_in[4];
    const float* b_ih  = (const float*)d_in[5];
    const float* b_hh  = (const float*)d_in[6];
    float* out = (float*)d_out;

    dim3 grid(BATCH / (16 * CHUNKS));  // 1024 persistent WGs, 4/CU
    dim3 block(256);
    Encoder_6949257085628_kernel<<<grid, block, 0, stream>>>(
        obs, W_emb, b_emb, W_ih, W_hh, b_ih, b_hh, out);
}